// Round 1
// baseline (250.158 us; speedup 1.0000x reference)
//
#include <hip/hip_runtime.h>

// LearnablePatchify: Conv2d(3->3, k=s=28) -> channel-mean -> broadcast per patch.
// Key algebra: mean over output channels commutes with the contraction, so
//   m[b,hp,wp] = sum_{c,i,j} x[b,c,hp*28+i,wp*28+j] * Wm[c,i,j] + bm
// with Wm = mean_o W[o,:,:,:] (2352 floats), bm = mean(b). Output = broadcast m.
// Shapes: x[64,3,448,448] f32, W[3,3,28,28], b[3], out[64,256,28,28] f32.
// Memory-bound: ~154 MB read + ~51 MB write -> ~33 us floor at 6.3 TB/s.

#define BLOCK 448   // 7 waves; one block per (b, hp) strip of 16 patches

__global__ __launch_bounds__(BLOCK) void patchify_kernel(
    const float* __restrict__ x, const float* __restrict__ W,
    const float* __restrict__ bias, float* __restrict__ out) {
  const int blk = blockIdx.x;   // 0..1023
  const int b   = blk >> 4;     // batch
  const int hp  = blk & 15;     // patch row

  __shared__ float  sWm[2352];        // mean-over-o weights [c][i][j]
  __shared__ float4 scol[4][112];     // per row-group, per float4-column partials
  __shared__ float  sm[16];           // per-patch results
  __shared__ float  sBm;

  const int t = threadIdx.x;

  // Wm = mean over the 3 output channels (W is 28 KB, L2-resident)
  for (int i = t; i < 2352; i += BLOCK)
    sWm[i] = (W[i] + W[2352 + i] + W[4704 + i]) * (1.0f / 3.0f);
  if (t == 0) sBm = (bias[0] + bias[1] + bias[2]) * (1.0f / 3.0f);
  __syncthreads();

  // Thread owns float4-column q (cols 4q..4q+3) and row-group r0 (rows r0,r0+4,...).
  // 28 % 4 == 0 so a float4 never crosses a patch boundary.
  const int q  = t % 112;       // 0..111 float4 columns across width 448
  const int r0 = t / 112;       // 0..3
  const int jm = (4 * q) % 28;  // within-patch column of this float4

  float4 acc = make_float4(0.f, 0.f, 0.f, 0.f);
  #pragma unroll
  for (int r = r0; r < 84; r += 4) {   // 84 rows = 3 channels x 28 patch rows
    const int c = r / 28;
    const int i = r % 28;
    const float4* row = reinterpret_cast<const float4*>(
        x + ((size_t)(b * 3 + c) * 448 + (size_t)(hp * 28 + i)) * 448);
    const float4 v = row[q];                       // coalesced 16B/lane
    const float* w = &sWm[c * 784 + i * 28 + jm];  // 7 distinct addrs/wave -> broadcast
    acc.x += v.x * w[0];
    acc.y += v.y * w[1];
    acc.z += v.z * w[2];
    acc.w += v.w * w[3];
  }
  scol[r0][q] = acc;
  __syncthreads();

  // Patch wp sum = over 4 row-groups x 7 float4-columns x 4 lanes
  if (t < 16) {
    float s = 0.f;
    for (int g = 0; g < 4; ++g) {
      #pragma unroll
      for (int k = 0; k < 7; ++k) {
        const float4 v = scol[g][t * 7 + k];
        s += (v.x + v.y) + (v.z + v.w);
      }
    }
    sm[t] = s + sBm;
  }
  __syncthreads();

  // Block's 16 patches are contiguous in out: base (b*256 + hp*16)*784, 12544 floats.
  float4* o4 = reinterpret_cast<float4*>(out + (size_t)(b * 256 + hp * 16) * 784);
  for (int idx = t; idx < 3136; idx += BLOCK) {  // exactly 7 iters/thread
    const float m = sm[idx / 196];               // 196 float4 per patch
    o4[idx] = make_float4(m, m, m, m);
  }
}

extern "C" void kernel_launch(void* const* d_in, const int* in_sizes, int n_in,
                              void* d_out, int out_size, void* d_ws, size_t ws_size,
                              hipStream_t stream) {
  const float* x    = (const float*)d_in[0];
  const float* W    = (const float*)d_in[1];
  const float* bias = (const float*)d_in[2];
  // d_in[3] = patch_size (scalar, ==28) — hard-coded above.
  float* out = (float*)d_out;
  patchify_kernel<<<dim3(1024), dim3(BLOCK), 0, stream>>>(x, W, bias, out);
}

// Round 2
// 236.225 us; speedup vs baseline: 1.0590x; 1.0590x over previous
//
#include <hip/hip_runtime.h>

// LearnablePatchify: Conv2d(3->3, k=s=28) -> channel-mean -> broadcast per patch.
// Algebra: channel-mean commutes with the contraction:
//   m[b,hp,wp] = sum_{c,i,j} x[b,c,hp*28+i,wp*28+j] * Wm[c,i,j] + bm,
//   Wm = mean_o W[o], bm = mean(b); out[b, hp*16+wp, :, :] = m (broadcast).
// x[64,3,448,448] f32 (154 MB), out[64,256,28,28] f32 (51 MB) -> memory-bound.
//
// Structure: one WAVE per patch (16384 patches, 4 waves/block, 4096 blocks).
// Patch input = 588 float4; lane l takes fragments f = it*64+l (10 iters, last
// partial). Strip-relative byte offsets precomputed in LDS (no div/mod in the
// hot loop). Butterfly shfl_xor reduce (no barrier, no LDS reduce). Output
// patch is 3136 contiguous bytes -> 4 coalesced NT float4 stores per lane.

#define BLOCK 256
#define NF 588  // float4 fragments per patch: 3*28*28/4

typedef float f32x4 __attribute__((ext_vector_type(4)));

__global__ __launch_bounds__(BLOCK) void patchify_kernel(
    const float* __restrict__ x, const float* __restrict__ W,
    const float* __restrict__ bias, float* __restrict__ out) {
  __shared__ float4 sW4[NF];  // mean-over-o weights, float4-fragment order
  __shared__ int    sT[NF];   // byte offset of fragment f within a patch strip

  const int t = threadIdx.x;

  // Prep: Wm fragments + offset table. W is 28 KB -> L2-resident across blocks.
  for (int f = t; f < NF; f += BLOCK) {
    const float4 a = reinterpret_cast<const float4*>(W)[f];
    const float4 g = reinterpret_cast<const float4*>(W)[f + NF];
    const float4 h = reinterpret_cast<const float4*>(W)[f + 2 * NF];
    sW4[f] = make_float4((a.x + g.x + h.x) * (1.f / 3.f),
                         (a.y + g.y + h.y) * (1.f / 3.f),
                         (a.z + g.z + h.z) * (1.f / 3.f),
                         (a.w + g.w + h.w) * (1.f / 3.f));
    const int c   = f / 196;          // channel (196 = 28*28/4 frags/channel)
    const int rem = f - c * 196;
    const int i   = rem / 7;          // patch row (7 float4 per 28-col row)
    const int j4  = rem - i * 7;      // float4 col within patch
    sT[f] = (c * 200704 + i * 448 + j4 * 4) * 4;  // byte offset in strip
  }
  __syncthreads();  // the ONLY barrier; waves are independent afterwards

  const int lane = t & 63;
  const int P    = blockIdx.x * 4 + (t >> 6);  // patch id 0..16383
  const int b    = P >> 8;
  const int rem  = P & 255;
  const int hp   = rem >> 4;
  const int wp   = rem & 15;

  const char* xbase = reinterpret_cast<const char*>(
      x + (size_t)b * 602112 + (size_t)(hp * 28) * 448 + wp * 28);

  float s = 0.f;
  #pragma unroll
  for (int it = 0; it < 9; ++it) {  // 9 full iterations: f = it*64+lane < 576
    const int f = it * 64 + lane;
    const float4 v = *reinterpret_cast<const float4*>(xbase + sT[f]);
    const float4 w = sW4[f];
    s += v.x * w.x + v.y * w.y + v.z * w.z + v.w * w.w;
  }
  {  // tail: f = 576+lane, valid for lanes 0..11
    const int f = 576 + lane;
    if (f < NF) {
      const float4 v = *reinterpret_cast<const float4*>(xbase + sT[f]);
      const float4 w = sW4[f];
      s += v.x * w.x + v.y * w.y + v.z * w.z + v.w * w.w;
    }
  }

  // 64-lane butterfly sum; all lanes end with the total.
  #pragma unroll
  for (int m = 32; m >= 1; m >>= 1) s += __shfl_xor(s, m, 64);
  s += (bias[0] + bias[1] + bias[2]) * (1.f / 3.f);

  // Broadcast-write the patch: 196 float4, contiguous. NT stores keep L3 for x.
  f32x4* o4 = reinterpret_cast<f32x4*>(out + (size_t)P * 784);
  const f32x4 val = {s, s, s, s};
  #pragma unroll
  for (int it = 0; it < 4; ++it) {
    const int idx = it * 64 + lane;
    if (idx < 196) __builtin_nontemporal_store(val, o4 + idx);
  }
}

extern "C" void kernel_launch(void* const* d_in, const int* in_sizes, int n_in,
                              void* d_out, int out_size, void* d_ws, size_t ws_size,
                              hipStream_t stream) {
  const float* x    = (const float*)d_in[0];
  const float* W    = (const float*)d_in[1];
  const float* bias = (const float*)d_in[2];
  float* out = (float*)d_out;
  patchify_kernel<<<dim3(4096), dim3(BLOCK), 0, stream>>>(x, W, bias, out);
}